// Round 4
// baseline (182.903 us; speedup 1.0000x reference)
//
#include <hip/hip_runtime.h>
#include <hip/hip_bf16.h>

#define DNBR   16
#define INDIM  128
#define OUTDIM 64

typedef __attribute__((ext_vector_type(8))) short bf16x8;
typedef __attribute__((ext_vector_type(4))) float f32x4;
typedef __attribute__((ext_vector_type(4))) unsigned u32x4;

union BF8 { bf16x8 v; u32x4 u; };

__device__ __forceinline__ unsigned cvt_pk_bf16(float lo, float hi) {
    unsigned r;
    asm("v_cvt_pk_bf16_f32 %0, %1, %2" : "=v"(r) : "v"(lo), "v"(hi));
    return r;
}

// ---------------- Phase 0: pre-pack W_fc into MFMA B-fragment order (bf16) ----
// slot(ct,kk,lane): 8 bf16 = 4 u32 at wfrag[((ct*4+kk)*64+lane)*4]
// element j = W_fc[ct*16+lm][kk*32+lg*8+j]  (lm=lane&15, lg=lane>>4)
__global__ __launch_bounds__(256) void wprep(
    const float* __restrict__ W_fc, unsigned* __restrict__ wfrag)
{
    const int t = threadIdx.x;
    #pragma unroll
    for (int s4 = 0; s4 < 4; ++s4) {
        const int slot = t + 256 * s4;        // 0..1023
        const int lane = slot & 63;
        const int ckk  = slot >> 6;           // ct*4+kk
        const int ct = ckk >> 2, kk = ckk & 3;
        const int lm = lane & 15, lg = lane >> 4;
        const float* wr = W_fc + (size_t)(ct * 16 + lm) * INDIM + kk * 32 + lg * 8;
        const float4 w0 = *reinterpret_cast<const float4*>(wr);
        const float4 w1 = *reinterpret_cast<const float4*>(wr + 4);
        u32x4 o;
        o[0] = cvt_pk_bf16(w0.x, w0.y);
        o[1] = cvt_pk_bf16(w0.z, w0.w);
        o[2] = cvt_pk_bf16(w1.x, w1.y);
        o[3] = cvt_pk_bf16(w1.z, w1.w);
        *reinterpret_cast<u32x4*>(wfrag + (size_t)slot * 4) = o;
    }
}

// ---------------- Phase 1: z = h @ W_fc^T via bf16 MFMA, + s_src/s_dst -------
// One wave = 16 rows x 64 cols. B fragments pre-packed (L1-resident 16 KB).
__global__ __launch_bounds__(256) void fc_mfma(
    const float* __restrict__ h, const unsigned* __restrict__ wfrag,
    const float* __restrict__ W_attn, __hip_bfloat16* __restrict__ zb,
    float* __restrict__ s_src, float* __restrict__ s_dst, int n)
{
    const int lane  = threadIdx.x & 63;
    const int wid   = threadIdx.x >> 6;
    const int node0 = blockIdx.x * 64 + wid * 16;
    if (node0 >= n) return;
    const int lm = lane & 15;
    const int lg = lane >> 4;

    // B fragments: 16 x dwordx4 loads, no conversion
    bf16x8 bfrag[4][4];
    #pragma unroll
    for (int ct = 0; ct < 4; ++ct)
        #pragma unroll
        for (int kk = 0; kk < 4; ++kk) {
            BF8 u;
            u.u = *reinterpret_cast<const u32x4*>(wfrag + (size_t)((ct * 4 + kk) * 64 + lane) * 4);
            bfrag[ct][kk] = u.v;
        }

    // A: row = node0 + lm (clamped; garbage rows never stored)
    const int arow = (node0 + lm < n) ? (node0 + lm) : (n - 1);
    const float* hr = h + (size_t)arow * INDIM;
    bf16x8 af[4];
    #pragma unroll
    for (int kk = 0; kk < 4; ++kk) {
        const float4 a0 = *reinterpret_cast<const float4*>(hr + kk * 32 + lg * 8);
        const float4 a1 = *reinterpret_cast<const float4*>(hr + kk * 32 + lg * 8 + 4);
        BF8 u;
        u.u[0] = cvt_pk_bf16(a0.x, a0.y);
        u.u[1] = cvt_pk_bf16(a0.z, a0.w);
        u.u[2] = cvt_pk_bf16(a1.x, a1.y);
        u.u[3] = cvt_pk_bf16(a1.z, a1.w);
        af[kk] = u.v;
    }

    f32x4 acc[4];
    #pragma unroll
    for (int ct = 0; ct < 4; ++ct) acc[ct] = (f32x4){0.f, 0.f, 0.f, 0.f};
    #pragma unroll
    for (int kk = 0; kk < 4; ++kk)
        #pragma unroll
        for (int ct = 0; ct < 4; ++ct)
            acc[ct] = __builtin_amdgcn_mfma_f32_16x16x32_bf16(af[kk], bfrag[ct][kk], acc[ct], 0, 0, 0);

    // Epilogue: z store (bf16) + attention-score partials, reduce over lm
    float ps[4] = {0.f, 0.f, 0.f, 0.f};
    float pd[4] = {0.f, 0.f, 0.f, 0.f};
    unsigned short* zbs = reinterpret_cast<unsigned short*>(zb);
    #pragma unroll
    for (int ct = 0; ct < 4; ++ct) {
        const float as = W_attn[ct * 16 + lm];
        const float ad = W_attn[OUTDIM + ct * 16 + lm];
        #pragma unroll
        for (int r = 0; r < 4; ++r) {
            const float v = acc[ct][r];                 // C[(lg*4+r)][ct*16+lm]
            const int grow = node0 + lg * 4 + r;
            if (grow < n)
                zbs[(size_t)grow * OUTDIM + ct * 16 + lm] =
                    (unsigned short)(cvt_pk_bf16(v, v) & 0xFFFFu);
            ps[r] = fmaf(v, as, ps[r]);
            pd[r] = fmaf(v, ad, pd[r]);
        }
    }
    #pragma unroll
    for (int off = 1; off < 16; off <<= 1) {
        #pragma unroll
        for (int r = 0; r < 4; ++r) {
            ps[r] += __shfl_xor(ps[r], off, 64);
            pd[r] += __shfl_xor(pd[r], off, 64);
        }
    }
    if (lm == 0) {
        #pragma unroll
        for (int r = 0; r < 4; ++r) {
            const int grow = node0 + lg * 4 + r;
            if (grow < n) { s_src[grow] = ps[r]; s_dst[grow] = pd[r]; }
        }
    }
}

// ---------------- exact entmax15 over 16 values (weights = y^2) ---------------
__device__ __forceinline__ void entmax15_weights(float x[DNBR], float wout[DNBR]) {
    float mx = x[0];
    #pragma unroll
    for (int j = 1; j < DNBR; ++j) mx = fmaxf(mx, x[j]);
    #pragma unroll
    for (int j = 0; j < DNBR; ++j) x[j] -= mx;

    float xs[DNBR];
    #pragma unroll
    for (int j = 0; j < DNBR; ++j) xs[j] = x[j];
    #pragma unroll
    for (int k = 2; k <= DNBR; k <<= 1) {
        #pragma unroll
        for (int s = k >> 1; s >= 1; s >>= 1) {
            #pragma unroll
            for (int i = 0; i < DNBR; ++i) {
                int l = i ^ s;
                if (l > i) {
                    const bool up = ((i & k) == 0);
                    float a = xs[i], b = xs[l];
                    float hi = fmaxf(a, b), lo = fminf(a, b);
                    xs[i] = up ? hi : lo;
                    xs[l] = up ? lo : hi;
                }
            }
        }
    }

    float taus[DNBR];
    float cs = 0.f, css = 0.f;
    int supp = 0;
    #pragma unroll
    for (int k = 0; k < DNBR; ++k) {
        cs  += xs[k];
        css += xs[k] * xs[k];
        const float kk = (float)(k + 1);
        const float mean   = cs  / kk;
        const float meansq = css / kk;
        const float ssv    = kk * (meansq - mean * mean);
        const float delta  = (1.f - ssv) / kk;
        const float sq     = (delta > 0.f) ? sqrtf(delta) : 0.f;
        taus[k] = mean - sq;
        supp += (taus[k] <= xs[k]) ? 1 : 0;
    }
    float tau_star = taus[0];
    #pragma unroll
    for (int k = 1; k < DNBR; ++k)
        tau_star = (supp - 1 == k) ? taus[k] : tau_star;

    #pragma unroll
    for (int j = 0; j < DNBR; ++j) {
        const float y = fmaxf(x[j] - tau_star, 0.f);
        wout[j] = y * y;
    }
}

// ---------------- Phase 2: fused entmax + gather/weighted-sum -----------------
// Block = 4 waves; wave wid owns nodes [blk*64 + wid*16, +16).
// Phase A: lanes 0..15 compute entmax for one node each -> per-wave LDS slice.
// Phase B: whole wave gathers z rows and accumulates (2-node ILP).
// No barrier: same-wave DS RAW is in-order.
__global__ __launch_bounds__(256) void fused_out(
    const int* __restrict__ nbr, const float* __restrict__ wbias,
    const __hip_bfloat16* __restrict__ zb, const float* __restrict__ s_src,
    const float* __restrict__ s_dst, float* __restrict__ out, int n)
{
    __shared__ float alds[4][DNBR][DNBR + 1];
    const int lane = threadIdx.x & 63;
    const int wid  = threadIdx.x >> 6;
    const int base = blockIdx.x * 64 + wid * DNBR;
    if (base >= n) return;
    const int cnt = (n - base < DNBR) ? (n - base) : DNBR;

    if (lane < cnt) {
        const int node = base + lane;
        const int4*   nrow = reinterpret_cast<const int4*>(nbr + (size_t)node * DNBR);
        const float4* wrow = reinterpret_cast<const float4*>(wbias + (size_t)node * DNBR);
        const float sd = s_dst[node];
        float x[DNBR];
        #pragma unroll
        for (int q = 0; q < 4; ++q) {
            const int4 v   = nrow[q];
            const float4 t = wrow[q];
            const int   nb4[4] = {v.x, v.y, v.z, v.w};
            const float w4[4]  = {t.x, t.y, t.z, t.w};
            #pragma unroll
            for (int j = 0; j < 4; ++j) {
                float e = s_src[nb4[j]] + sd;
                e = (e >= 0.f) ? e : 0.01f * e;
                x[q * 4 + j] = 0.5f * (e + w4[j]);
            }
        }
        float wts[DNBR];
        entmax15_weights(x, wts);
        #pragma unroll
        for (int q = 0; q < DNBR; ++q) alds[wid][lane][q] = wts[q];
    }
    // same-wave LDS handoff; no __syncthreads needed

    #pragma unroll 2
    for (int i = 0; i < cnt; ++i) {
        const int node = base + i;
        const int4* nrow = reinterpret_cast<const int4*>(nbr + (size_t)node * DNBR);
        int nb[DNBR];
        #pragma unroll
        for (int q = 0; q < 4; ++q) {
            const int4 v = nrow[q];
            nb[q * 4 + 0] = v.x; nb[q * 4 + 1] = v.y;
            nb[q * 4 + 2] = v.z; nb[q * 4 + 3] = v.w;
        }
        float aw[DNBR];
        #pragma unroll
        for (int j = 0; j < DNBR; ++j) aw[j] = alds[wid][i][j];   // broadcast
        float acc = 0.f;
        #pragma unroll
        for (int j = 0; j < DNBR; ++j) {
            const float zj = __bfloat162float(zb[(size_t)nb[j] * OUTDIM + lane]);
            acc = fmaf(aw[j], zj, acc);
        }
        out[(size_t)node * OUTDIM + lane] = acc;
    }
}

extern "C" void kernel_launch(void* const* d_in, const int* in_sizes, int n_in,
                              void* d_out, int out_size, void* d_ws, size_t ws_size,
                              hipStream_t stream) {
    const float* h      = (const float*)d_in[0];
    const int*   nbr    = (const int*)  d_in[1];
    const float* wbias  = (const float*)d_in[2];
    const float* W_fc   = (const float*)d_in[3];
    const float* W_attn = (const float*)d_in[4];
    float* out = (float*)d_out;

    const int n = in_sizes[0] / INDIM;   // 100000

    // ws: zb (n*64 bf16) | s_src (n f32) | s_dst (n f32) | wfrag (4096 u32)
    __hip_bfloat16* zb = (__hip_bfloat16*)d_ws;
    float* s_src = (float*)((char*)d_ws + (size_t)n * OUTDIM * sizeof(__hip_bfloat16));
    float* s_dst = s_src + n;
    unsigned* wfrag = (unsigned*)(s_dst + n);

    const int blocks = (n + 63) / 64;
    wprep<<<1, 256, 0, stream>>>(W_fc, wfrag);
    fc_mfma<<<blocks, 256, 0, stream>>>(h, wfrag, W_attn, zb, s_src, s_dst, n);
    fused_out<<<blocks, 256, 0, stream>>>(nbr, wbias, zb, s_src, s_dst, out, n);
}

// Round 5
// 75.257 us; speedup vs baseline: 2.4304x; 2.4304x over previous
//
#include <hip/hip_runtime.h>
#include <hip/hip_bf16.h>

#define DNBR   16
#define INDIM  128
#define OUTDIM 64

typedef __attribute__((ext_vector_type(8))) short bf16x8;
typedef __attribute__((ext_vector_type(4))) float f32x4;
typedef __attribute__((ext_vector_type(4))) unsigned u32x4;

union BF8 { bf16x8 v; u32x4 u; };

__device__ __forceinline__ unsigned cvt_pk_bf16(float lo, float hi) {
    unsigned r;
    asm("v_cvt_pk_bf16_f32 %0, %1, %2" : "=v"(r) : "v"(lo), "v"(hi));
    return r;
}

// ---------------- Phase 0: pre-pack W_fc into MFMA B-fragment order (bf16) ----
__global__ __launch_bounds__(256) void wprep(
    const float* __restrict__ W_fc, unsigned* __restrict__ wfrag)
{
    const int t = threadIdx.x;
    #pragma unroll
    for (int s4 = 0; s4 < 4; ++s4) {
        const int slot = t + 256 * s4;        // 0..1023
        const int lane = slot & 63;
        const int ckk  = slot >> 6;           // ct*4+kk
        const int ct = ckk >> 2, kk = ckk & 3;
        const int lm = lane & 15, lg = lane >> 4;
        const float* wr = W_fc + (size_t)(ct * 16 + lm) * INDIM + kk * 32 + lg * 8;
        const float4 w0 = *reinterpret_cast<const float4*>(wr);
        const float4 w1 = *reinterpret_cast<const float4*>(wr + 4);
        u32x4 o;
        o[0] = cvt_pk_bf16(w0.x, w0.y);
        o[1] = cvt_pk_bf16(w0.z, w0.w);
        o[2] = cvt_pk_bf16(w1.x, w1.y);
        o[3] = cvt_pk_bf16(w1.z, w1.w);
        *reinterpret_cast<u32x4*>(wfrag + (size_t)slot * 4) = o;
    }
}

// ---------------- Phase 1: z = h @ W_fc^T via bf16 MFMA, + s_src/s_dst -------
__global__ __launch_bounds__(256) void fc_mfma(
    const float* __restrict__ h, const unsigned* __restrict__ wfrag,
    const float* __restrict__ W_attn, __hip_bfloat16* __restrict__ zb,
    float* __restrict__ s_src, float* __restrict__ s_dst, int n)
{
    const int lane  = threadIdx.x & 63;
    const int wid   = threadIdx.x >> 6;
    const int node0 = blockIdx.x * 64 + wid * 16;
    if (node0 >= n) return;
    const int lm = lane & 15;
    const int lg = lane >> 4;

    bf16x8 bfrag[4][4];
    #pragma unroll
    for (int ct = 0; ct < 4; ++ct)
        #pragma unroll
        for (int kk = 0; kk < 4; ++kk) {
            BF8 u;
            u.u = *reinterpret_cast<const u32x4*>(wfrag + (size_t)((ct * 4 + kk) * 64 + lane) * 4);
            bfrag[ct][kk] = u.v;
        }

    const int arow = (node0 + lm < n) ? (node0 + lm) : (n - 1);
    const float* hr = h + (size_t)arow * INDIM;
    bf16x8 af[4];
    #pragma unroll
    for (int kk = 0; kk < 4; ++kk) {
        const float4 a0 = *reinterpret_cast<const float4*>(hr + kk * 32 + lg * 8);
        const float4 a1 = *reinterpret_cast<const float4*>(hr + kk * 32 + lg * 8 + 4);
        BF8 u;
        u.u[0] = cvt_pk_bf16(a0.x, a0.y);
        u.u[1] = cvt_pk_bf16(a0.z, a0.w);
        u.u[2] = cvt_pk_bf16(a1.x, a1.y);
        u.u[3] = cvt_pk_bf16(a1.z, a1.w);
        af[kk] = u.v;
    }

    f32x4 acc[4];
    #pragma unroll
    for (int ct = 0; ct < 4; ++ct) acc[ct] = (f32x4){0.f, 0.f, 0.f, 0.f};
    #pragma unroll
    for (int kk = 0; kk < 4; ++kk)
        #pragma unroll
        for (int ct = 0; ct < 4; ++ct)
            acc[ct] = __builtin_amdgcn_mfma_f32_16x16x32_bf16(af[kk], bfrag[ct][kk], acc[ct], 0, 0, 0);

    float ps[4] = {0.f, 0.f, 0.f, 0.f};
    float pd[4] = {0.f, 0.f, 0.f, 0.f};
    unsigned short* zbs = reinterpret_cast<unsigned short*>(zb);
    #pragma unroll
    for (int ct = 0; ct < 4; ++ct) {
        const float as = W_attn[ct * 16 + lm];
        const float ad = W_attn[OUTDIM + ct * 16 + lm];
        #pragma unroll
        for (int r = 0; r < 4; ++r) {
            const float v = acc[ct][r];                 // C[(lg*4+r)][ct*16+lm]
            const int grow = node0 + lg * 4 + r;
            if (grow < n)
                zbs[(size_t)grow * OUTDIM + ct * 16 + lm] =
                    (unsigned short)(cvt_pk_bf16(v, v) & 0xFFFFu);
            ps[r] = fmaf(v, as, ps[r]);
            pd[r] = fmaf(v, ad, pd[r]);
        }
    }
    #pragma unroll
    for (int off = 1; off < 16; off <<= 1) {
        #pragma unroll
        for (int r = 0; r < 4; ++r) {
            ps[r] += __shfl_xor(ps[r], off, 64);
            pd[r] += __shfl_xor(pd[r], off, 64);
        }
    }
    if (lm == 0) {
        #pragma unroll
        for (int r = 0; r < 4; ++r) {
            const int grow = node0 + lg * 4 + r;
            if (grow < n) { s_src[grow] = ps[r]; s_dst[grow] = pd[r]; }
        }
    }
}

// ---------------- exact entmax15 over 16 values (weights = y^2) ---------------
__device__ __forceinline__ void entmax15_weights(float x[DNBR], float wout[DNBR]) {
    float mx = x[0];
    #pragma unroll
    for (int j = 1; j < DNBR; ++j) mx = fmaxf(mx, x[j]);
    #pragma unroll
    for (int j = 0; j < DNBR; ++j) x[j] -= mx;

    float xs[DNBR];
    #pragma unroll
    for (int j = 0; j < DNBR; ++j) xs[j] = x[j];
    #pragma unroll
    for (int k = 2; k <= DNBR; k <<= 1) {
        #pragma unroll
        for (int s = k >> 1; s >= 1; s >>= 1) {
            #pragma unroll
            for (int i = 0; i < DNBR; ++i) {
                int l = i ^ s;
                if (l > i) {
                    const bool up = ((i & k) == 0);
                    float a = xs[i], b = xs[l];
                    float hi = fmaxf(a, b), lo = fminf(a, b);
                    xs[i] = up ? hi : lo;
                    xs[l] = up ? lo : hi;
                }
            }
        }
    }

    float taus[DNBR];
    float cs = 0.f, css = 0.f;
    int supp = 0;
    #pragma unroll
    for (int k = 0; k < DNBR; ++k) {
        cs  += xs[k];
        css += xs[k] * xs[k];
        const float kk = (float)(k + 1);
        const float mean   = cs  / kk;
        const float meansq = css / kk;
        const float ssv    = kk * (meansq - mean * mean);
        const float delta  = (1.f - ssv) / kk;
        const float sq     = (delta > 0.f) ? sqrtf(delta) : 0.f;
        taus[k] = mean - sq;
        supp += (taus[k] <= xs[k]) ? 1 : 0;
    }
    float tau_star = taus[0];
    #pragma unroll
    for (int k = 1; k < DNBR; ++k)
        tau_star = (supp - 1 == k) ? taus[k] : tau_star;

    #pragma unroll
    for (int j = 0; j < DNBR; ++j) {
        const float y = fmaxf(x[j] - tau_star, 0.f);
        wout[j] = y * y;
    }
}

// ---------------- Phase 2: one thread per node -> alpha[n][16] ----------------
__global__ __launch_bounds__(256) void alpha_kernel(
    const int* __restrict__ nbr, const float* __restrict__ wbias,
    const float* __restrict__ s_src, const float* __restrict__ s_dst,
    float* __restrict__ alpha, int n)
{
    const int node = blockIdx.x * 256 + threadIdx.x;
    if (node >= n) return;

    const int4*   nrow = reinterpret_cast<const int4*>(nbr + (size_t)node * DNBR);
    const float4* wrow = reinterpret_cast<const float4*>(wbias + (size_t)node * DNBR);
    const float sd = s_dst[node];

    float x[DNBR];
    #pragma unroll
    for (int q = 0; q < 4; ++q) {
        const int4 v   = nrow[q];
        const float4 t = wrow[q];
        const int   nb4[4] = {v.x, v.y, v.z, v.w};
        const float w4[4]  = {t.x, t.y, t.z, t.w};
        #pragma unroll
        for (int j = 0; j < 4; ++j) {
            float e = s_src[nb4[j]] + sd;
            e = (e >= 0.f) ? e : 0.01f * e;
            x[q * 4 + j] = 0.5f * (e + w4[j]);
        }
    }

    float wts[DNBR];
    entmax15_weights(x, wts);

    float4* arow = reinterpret_cast<float4*>(alpha + (size_t)node * DNBR);
    #pragma unroll
    for (int q = 0; q < 4; ++q)
        arow[q] = make_float4(wts[q * 4 + 0], wts[q * 4 + 1], wts[q * 4 + 2], wts[q * 4 + 3]);
}

// ---------------- Phase 3: one wave per TWO nodes; 32 gathers in flight -------
__global__ __launch_bounds__(256) void out_kernel(
    const int* __restrict__ nbr, const float* __restrict__ alpha,
    const __hip_bfloat16* __restrict__ zb, float* __restrict__ out, int n)
{
    const int lane = threadIdx.x & 63;
    const int wv   = blockIdx.x * 4 + (threadIdx.x >> 6);
    const int n0   = wv * 2;
    if (n0 >= n) return;
    const int n1 = (n0 + 1 < n) ? (n0 + 1) : n0;

    // neighbor indices for both nodes (wave-uniform int4 loads)
    int nb0[DNBR], nb1[DNBR];
    const int4* r0 = reinterpret_cast<const int4*>(nbr + (size_t)n0 * DNBR);
    const int4* r1 = reinterpret_cast<const int4*>(nbr + (size_t)n1 * DNBR);
    #pragma unroll
    for (int q = 0; q < 4; ++q) {
        const int4 a = r0[q], b = r1[q];
        nb0[q*4+0]=a.x; nb0[q*4+1]=a.y; nb0[q*4+2]=a.z; nb0[q*4+3]=a.w;
        nb1[q*4+0]=b.x; nb1[q*4+1]=b.y; nb1[q*4+2]=b.z; nb1[q*4+3]=b.w;
    }

    // alpha for both nodes
    float aw0[DNBR], aw1[DNBR];
    const float4* a0 = reinterpret_cast<const float4*>(alpha + (size_t)n0 * DNBR);
    const float4* a1 = reinterpret_cast<const float4*>(alpha + (size_t)n1 * DNBR);
    #pragma unroll
    for (int q = 0; q < 4; ++q) {
        const float4 t0 = a0[q], t1 = a1[q];
        aw0[q*4+0]=t0.x; aw0[q*4+1]=t0.y; aw0[q*4+2]=t0.z; aw0[q*4+3]=t0.w;
        aw1[q*4+0]=t1.x; aw1[q*4+1]=t1.y; aw1[q*4+2]=t1.z; aw1[q*4+3]=t1.w;
    }

    // all 32 gathers issued before first use
    const unsigned short* zs = reinterpret_cast<const unsigned short*>(zb);
    unsigned short zv0[DNBR], zv1[DNBR];
    #pragma unroll
    for (int j = 0; j < DNBR; ++j) zv0[j] = zs[(size_t)nb0[j] * OUTDIM + lane];
    #pragma unroll
    for (int j = 0; j < DNBR; ++j) zv1[j] = zs[(size_t)nb1[j] * OUTDIM + lane];

    float acc0 = 0.f, acc1 = 0.f;
    #pragma unroll
    for (int j = 0; j < DNBR; ++j) {
        union { unsigned u; float f; } c0, c1;
        c0.u = (unsigned)zv0[j] << 16;
        c1.u = (unsigned)zv1[j] << 16;
        acc0 = fmaf(aw0[j], c0.f, acc0);
        acc1 = fmaf(aw1[j], c1.f, acc1);
    }
    out[(size_t)n0 * OUTDIM + lane] = acc0;
    if (n1 != n0) out[(size_t)n1 * OUTDIM + lane] = acc1;
}

extern "C" void kernel_launch(void* const* d_in, const int* in_sizes, int n_in,
                              void* d_out, int out_size, void* d_ws, size_t ws_size,
                              hipStream_t stream) {
    const float* h      = (const float*)d_in[0];
    const int*   nbr    = (const int*)  d_in[1];
    const float* wbias  = (const float*)d_in[2];
    const float* W_fc   = (const float*)d_in[3];
    const float* W_attn = (const float*)d_in[4];
    float* out = (float*)d_out;

    const int n = in_sizes[0] / INDIM;   // 100000

    // ws: zb (n*64 bf16) | s_src (n f32) | s_dst (n f32) | alpha (n*16 f32) | wfrag (4096 u32)
    __hip_bfloat16* zb = (__hip_bfloat16*)d_ws;
    float* s_src = (float*)((char*)d_ws + (size_t)n * OUTDIM * sizeof(__hip_bfloat16));
    float* s_dst = s_src + n;
    float* alpha = s_dst + n;
    unsigned* wfrag = (unsigned*)(alpha + (size_t)n * DNBR);

    wprep<<<1, 256, 0, stream>>>(W_fc, wfrag);
    fc_mfma<<<(n + 63) / 64, 256, 0, stream>>>(h, wfrag, W_attn, zb, s_src, s_dst, n);
    alpha_kernel<<<(n + 255) / 256, 256, 0, stream>>>(nbr, wbias, s_src, s_dst, alpha, n);
    out_kernel<<<(n + 7) / 8, 256, 0, stream>>>(nbr, alpha, zb, out, n);
}